// Round 1
// baseline (755.280 us; speedup 1.0000x reference)
//
#include <hip/hip_runtime.h>
#include <math.h>

// ---------------------------------------------------------------------------
// EnvelopeDetector: depthwise conv1d(K=100) -> BatchNorm(train) -> abs ->
//                   depthwise conv1d(K=50) + bias
// x:[32,64,20000] f32 -> out:[32,64,19852] f32
// ---------------------------------------------------------------------------

constexpr int B_ = 32, C_ = 64, T_ = 20000;
constexpr int K1 = 100, K2 = 50;
constexpr int T1 = T_ - K1 + 1;   // 19901
constexpr int T2 = T1 - K2 + 1;   // 19852
constexpr int TY = 19904;         // padded y row stride (multiple of 4)
constexpr float EPS = 1e-5f;

constexpr int BLK = 256;
constexpr int R = 8;                      // outputs per thread (consecutive)
constexpr int TILE = BLK * R;             // 2048 outputs per block
constexpr int NCH1 = (T1 + TILE - 1) / TILE;  // 10
constexpr int NCH2 = (T2 + TILE - 1) / TILE;  // 10

#define DEVFN __device__ __forceinline__

// Sliding-window FIR: thread computes R consecutive outputs from LDS.
// xs must be 16B aligned; toff = tid*R (32B aligned). wsm padded to >= K+8.
template <int K>
DEVFN void fir_window(const float* __restrict__ xs,
                      const float* __restrict__ wsm,
                      int toff, float acc[R]) {
  float xw[R];
  *(float4*)&xw[0] = *(const float4*)&xs[toff];
  *(float4*)&xw[4] = *(const float4*)&xs[toff + 4];
#pragma unroll
  for (int r = 0; r < R; ++r) acc[r] = 0.f;

  constexpr int KM = (K / R) * R;
  for (int k = 0; k < KM; k += R) {
    float nv[R], wv[R];
    *(float4*)&nv[0] = *(const float4*)&xs[toff + k + R];
    *(float4*)&nv[4] = *(const float4*)&xs[toff + k + R + 4];
    *(float4*)&wv[0] = *(const float4*)&wsm[k];
    *(float4*)&wv[4] = *(const float4*)&wsm[k + 4];
#pragma unroll
    for (int kk = 0; kk < R; ++kk) {
#pragma unroll
      for (int r = 0; r < R; ++r)
        acc[r] = fmaf(xw[(kk + r) & (R - 1)], wv[kk], acc[r]);
      xw[kk] = nv[kk];
    }
  }
  if constexpr (KM < K) {
    float wv[4];
    *(float4*)&wv[0] = *(const float4*)&wsm[KM];  // wsm padded; slop unused
#pragma unroll
    for (int kk = 0; kk < K - KM; ++kk) {
#pragma unroll
      for (int r = 0; r < R; ++r)
        acc[r] = fmaf(xw[(kk + r) & (R - 1)], wv[kk], acc[r]);
      if (kk + 1 < K - KM) xw[kk] = xs[toff + KM + kk + R];
    }
  }
}

__global__ void zero_stats(float* __restrict__ s) { s[threadIdx.x] = 0.f; }

// Kernel A: depthwise conv1 (K1 taps), per-channel sum/sumsq, optional y store.
template <bool STORE_Y>
__global__ __launch_bounds__(BLK) void conv1_stats(
    const float* __restrict__ x, const float* __restrict__ wband,
    float* __restrict__ y, float* __restrict__ stats) {
  __shared__ alignas(16) float xs[TILE + K1 + 8];   // 2155
  __shared__ alignas(16) float wsm[K1 + 8];
  __shared__ float red[(BLK / 64) * 2];

  const int tid = threadIdx.x;
  const int chunk = blockIdx.x, c = blockIdx.y, b = blockIdx.z;
  const int t0 = chunk * TILE;
  const int TL = min(TILE, T1 - t0);     // valid outputs this block
  const int stage = TL + K1 - 1;         // x values needed
  const long xbase = ((long)(b * C_ + c)) * T_ + t0;

  for (int i = tid; i < K1; i += BLK) wsm[i] = wband[c * K1 + i];
  for (int i = tid; i < TILE + K1 + 8; i += BLK)
    xs[i] = (i < stage) ? x[xbase + i] : 0.f;
  __syncthreads();

  const int toff = tid * R;
  float acc[R];
  fir_window<K1>(xs, wsm, toff, acc);

  // per-channel stats over valid outputs
  float s1 = 0.f, s2 = 0.f;
#pragma unroll
  for (int r = 0; r < R; ++r) {
    const float yv = (toff + r < TL) ? acc[r] : 0.f;
    s1 += yv;
    s2 = fmaf(yv, yv, s2);
  }
#pragma unroll
  for (int off = 32; off > 0; off >>= 1) {
    s1 += __shfl_down(s1, off);
    s2 += __shfl_down(s2, off);
  }
  const int wid = tid >> 6;
  if ((tid & 63) == 0) { red[wid * 2] = s1; red[wid * 2 + 1] = s2; }
  __syncthreads();
  if (tid == 0) {
    float a = 0.f, bsum = 0.f;
#pragma unroll
    for (int w = 0; w < BLK / 64; ++w) { a += red[w * 2]; bsum += red[w * 2 + 1]; }
    atomicAdd(&stats[c], a);
    atomicAdd(&stats[C_ + c], bsum);
  }

  if constexpr (STORE_Y) {
    const long ybase = ((long)(b * C_ + c)) * TY + t0 + toff;
    if (toff + R <= TL) {
      *(float4*)&y[ybase] = *(float4*)&acc[0];
      *(float4*)&y[ybase + 4] = *(float4*)&acc[4];
    } else {
#pragma unroll
      for (int r = 0; r < R; ++r)
        if (toff + r < TL) y[ybase + r] = acc[r];
    }
  }
}

// Kernel B: stats -> per-channel scale/shift
__global__ void finalize_stats(const float* __restrict__ stats,
                               const float* __restrict__ gamma,
                               const float* __restrict__ beta,
                               float* __restrict__ ss) {
  const int c = threadIdx.x;
  if (c < C_) {
    const double N = (double)B_ * (double)T1;
    const double mean = (double)stats[c] / N;
    const double var = (double)stats[C_ + c] / N - mean * mean;
    const float scale = gamma[c] * (float)(1.0 / sqrt(var + (double)EPS));
    const float shift = beta[c] - (float)mean * scale;
    ss[c] = scale;
    ss[C_ + c] = shift;
  }
}

// Kernel C: u = |y*scale+shift| ; out = conv(u, wlow) + blow
// RECOMP=false: yin = padded y buffer. RECOMP=true: yin = x (recompute conv1).
template <bool RECOMP>
__global__ __launch_bounds__(BLK) void bn_abs_conv2(
    const float* __restrict__ yin, const float* __restrict__ wband,
    const float* __restrict__ wlow, const float* __restrict__ blow,
    const float* __restrict__ ss, float* __restrict__ out) {
  __shared__ alignas(16) float us[TILE + K2 + 8];   // 2106
  __shared__ alignas(16) float wsm2[K2 + 8];

  const int tid = threadIdx.x;
  const int chunk = blockIdx.x, c = blockIdx.y, b = blockIdx.z;
  const int t0 = chunk * TILE;
  const int TL = min(TILE, T2 - t0);   // valid outputs
  const int UL = TL + K2 - 1;          // u values needed
  const float scale = ss[c], shift = ss[C_ + c];

  for (int i = tid; i < K2; i += BLK) wsm2[i] = wlow[c * K2 + i];

  if constexpr (!RECOMP) {
    const long ybase = ((long)(b * C_ + c)) * TY + t0;
    for (int i = tid; i < TILE + K2 + 8; i += BLK) {
      const float yv = (i < UL) ? yin[ybase + i] : 0.f;
      us[i] = fabsf(fmaf(yv, scale, shift));
    }
    __syncthreads();
  } else {
    __shared__ alignas(16) float xs2[TILE + K2 + K1 + 8];  // 2205
    __shared__ alignas(16) float wsm1[K1 + 8];
    const int XL = UL + K1 - 1;
    const long xbase = ((long)(b * C_ + c)) * T_ + t0;
    for (int i = tid; i < K1; i += BLK) wsm1[i] = wband[c * K1 + i];
    for (int i = tid; i < TILE + K2 + K1 + 8; i += BLK)
      xs2[i] = (i < XL) ? yin[xbase + i] : 0.f;
    __syncthreads();
    {
      const int toff = tid * R;
      float acc[R];
      fir_window<K1>(xs2, wsm1, toff, acc);
#pragma unroll
      for (int r = 0; r < R; ++r)
        us[toff + r] = fabsf(fmaf(acc[r], scale, shift));
      if (tid < K2 - 1) {          // tail u positions TILE..TILE+K2-2
        const int p = TILE + tid;
        if (p < UL) {
          float a = 0.f;
          for (int k = 0; k < K1; ++k) a = fmaf(xs2[p + k], wsm1[k], a);
          us[p] = fabsf(fmaf(a, scale, shift));
        }
      }
    }
    __syncthreads();
  }

  const int toff = tid * R;
  float acc[R];
  fir_window<K2>(us, wsm2, toff, acc);
  const float bl = blow[c];
#pragma unroll
  for (int r = 0; r < R; ++r) acc[r] += bl;

  const long obase = ((long)(b * C_ + c)) * T2 + t0 + toff;
  if (toff + R <= TL) {
    *(float4*)&out[obase] = *(float4*)&acc[0];
    *(float4*)&out[obase + 4] = *(float4*)&acc[4];
  } else {
#pragma unroll
    for (int r = 0; r < R; ++r)
      if (toff + r < TL) out[obase + r] = acc[r];
  }
}

extern "C" void kernel_launch(void* const* d_in, const int* in_sizes, int n_in,
                              void* d_out, int out_size, void* d_ws, size_t ws_size,
                              hipStream_t stream) {
  const float* x = (const float*)d_in[0];
  const float* wband = (const float*)d_in[1];
  const float* gamma = (const float*)d_in[2];
  const float* beta = (const float*)d_in[3];
  const float* wlow = (const float*)d_in[4];
  const float* blow = (const float*)d_in[5];
  float* out = (float*)d_out;
  float* ws = (float*)d_ws;

  const size_t yfloats = (size_t)B_ * C_ * TY;            // 40,763,392
  const bool bigws = ws_size >= (yfloats + 256) * sizeof(float);

  float* ybuf = ws;
  float* stats = bigws ? (ws + yfloats) : ws;   // 128 floats: sum, sumsq
  float* ss = stats + 128;                      // 128 floats: scale, shift

  zero_stats<<<1, 128, 0, stream>>>(stats);

  dim3 grid1(NCH1, C_, B_);
  if (bigws)
    conv1_stats<true><<<grid1, BLK, 0, stream>>>(x, wband, ybuf, stats);
  else
    conv1_stats<false><<<grid1, BLK, 0, stream>>>(x, wband, nullptr, stats);

  finalize_stats<<<1, 64, 0, stream>>>(stats, gamma, beta, ss);

  dim3 grid2(NCH2, C_, B_);
  if (bigws)
    bn_abs_conv2<false><<<grid2, BLK, 0, stream>>>(ybuf, wband, wlow, blow, ss, out);
  else
    bn_abs_conv2<true><<<grid2, BLK, 0, stream>>>(x, wband, wlow, blow, ss, out);
}

// Round 2
// 465.955 us; speedup vs baseline: 1.6209x; 1.6209x over previous
//
#include <hip/hip_runtime.h>
#include <math.h>

// ---------------------------------------------------------------------------
// EnvelopeDetector: depthwise conv1d(K=100) -> BatchNorm(train) -> abs ->
//                   depthwise conv1d(K=50) + bias
// x:[32,64,20000] f32 -> out:[32,64,19852] f32
// R2: XOR-swizzled LDS (kills 16-way bank conflict of strided window refill)
//     + R=16 outputs/thread (halves LDS refill traffic per output)
// ---------------------------------------------------------------------------

constexpr int B_ = 32, C_ = 64, T_ = 20000;
constexpr int K1 = 100, K2 = 50;
constexpr int T1 = T_ - K1 + 1;   // 19901
constexpr int T2 = T1 - K2 + 1;   // 19852
constexpr int TY = 19904;         // padded y row stride (multiple of 4)
constexpr float EPS = 1e-5f;

constexpr int BLK = 256;
constexpr int R = 16;                     // outputs per thread (consecutive)
constexpr int TILE = BLK * R;             // 4096 outputs per block
constexpr int NCH1 = (T1 + TILE - 1) / TILE;  // 5
constexpr int NCH2 = (T2 + TILE - 1) / TILE;  // 5

constexpr int pad32(int n) { return (n + 31) & ~31; }  // keep XOR bijective
constexpr int SZ1 = pad32(TILE + K1 + 8);             // 4224
constexpr int SZU = pad32(TILE + K2 + 8);             // 4160
constexpr int SZ2 = pad32(TILE + K2 + K1 + 8);        // 4256

#define DEVFN __device__ __forceinline__

// ---- XOR-swizzled LDS accessors (swizzle in float4-group space) -----------
DEVFN int swzF(int i) { int F = i >> 2; return F ^ ((F >> 3) & 7); }
DEVFN float4 lds_ld4(const float* __restrict__ s, int i) {   // i % 4 == 0
  return *(const float4*)&s[swzF(i) << 2];
}
DEVFN void lds_st4(float* __restrict__ s, int i, float4 v) { // i % 4 == 0
  *(float4*)&s[swzF(i) << 2] = v;
}
DEVFN float lds_ld(const float* __restrict__ s, int i) {
  return s[(swzF(i) << 2) | (i & 3)];
}
DEVFN void lds_st(float* __restrict__ s, int i, float v) {
  s[(swzF(i) << 2) | (i & 3)] = v;
}

// Sliding-window FIR: thread computes R consecutive outputs from swizzled LDS.
// toff = tid*R. wsm (weights, broadcast reads) is NOT swizzled; padded >= K+4.
template <int K>
DEVFN void fir_window(const float* __restrict__ xs,
                      const float* __restrict__ wsm,
                      int toff, float acc[R]) {
  float xw[R];
#pragma unroll
  for (int q = 0; q < R; q += 4) *(float4*)&xw[q] = lds_ld4(xs, toff + q);
#pragma unroll
  for (int r = 0; r < R; ++r) acc[r] = 0.f;

  constexpr int KM = (K / R) * R;
  for (int k = 0; k < KM; k += R) {
    float nv[R], wv[R];
#pragma unroll
    for (int q = 0; q < R; q += 4) {
      *(float4*)&nv[q] = lds_ld4(xs, toff + k + R + q);
      *(float4*)&wv[q] = *(const float4*)&wsm[k + q];
    }
#pragma unroll
    for (int kk = 0; kk < R; ++kk) {
#pragma unroll
      for (int r = 0; r < R; ++r)
        acc[r] = fmaf(xw[(kk + r) & (R - 1)], wv[kk], acc[r]);
      xw[kk] = nv[kk];
    }
  }
  if constexpr (KM < K) {
    static_assert(K - KM <= 4, "tail fits one float4 of weights");
    float wv4[4];
    *(float4*)&wv4[0] = *(const float4*)&wsm[KM];
#pragma unroll
    for (int kk = 0; kk < K - KM; ++kk) {
#pragma unroll
      for (int r = 0; r < R; ++r)
        acc[r] = fmaf(xw[(kk + r) & (R - 1)], wv4[kk], acc[r]);
      if (kk + 1 < K - KM) xw[kk] = lds_ld(xs, toff + KM + kk + R);
    }
  }
}

__global__ void zero_stats(float* __restrict__ s) { s[threadIdx.x] = 0.f; }

// Kernel A: depthwise conv1 (K1 taps), per-channel sum/sumsq, optional y store.
template <bool STORE_Y>
__global__ __launch_bounds__(BLK) void conv1_stats(
    const float* __restrict__ x, const float* __restrict__ wband,
    float* __restrict__ y, float* __restrict__ stats) {
  __shared__ alignas(16) float xs[SZ1];
  __shared__ alignas(16) float wsm[K1 + 16];
  __shared__ float red[(BLK / 64) * 2];

  const int tid = threadIdx.x;
  const int chunk = blockIdx.x, c = blockIdx.y, b = blockIdx.z;
  const int t0 = chunk * TILE;
  const int TL = min(TILE, T1 - t0);     // valid outputs this block
  const int stage = TL + K1 - 1;         // x values needed
  const long xbase = ((long)(b * C_ + c)) * T_ + t0;

  for (int i = tid; i < K1; i += BLK) wsm[i] = wband[c * K1 + i];
  for (int i = tid * 4; i < SZ1; i += BLK * 4) {
    float4 v;
    if (i + 4 <= stage) v = *(const float4*)&x[xbase + i];
    else {
      v.x = (i + 0 < stage) ? x[xbase + i + 0] : 0.f;
      v.y = (i + 1 < stage) ? x[xbase + i + 1] : 0.f;
      v.z = (i + 2 < stage) ? x[xbase + i + 2] : 0.f;
      v.w = (i + 3 < stage) ? x[xbase + i + 3] : 0.f;
    }
    lds_st4(xs, i, v);
  }
  __syncthreads();

  const int toff = tid * R;
  float acc[R];
  fir_window<K1>(xs, wsm, toff, acc);

  // per-channel stats over valid outputs
  float s1 = 0.f, s2 = 0.f;
#pragma unroll
  for (int r = 0; r < R; ++r) {
    const float yv = (toff + r < TL) ? acc[r] : 0.f;
    s1 += yv;
    s2 = fmaf(yv, yv, s2);
  }
#pragma unroll
  for (int off = 32; off > 0; off >>= 1) {
    s1 += __shfl_down(s1, off);
    s2 += __shfl_down(s2, off);
  }
  const int wid = tid >> 6;
  if ((tid & 63) == 0) { red[wid * 2] = s1; red[wid * 2 + 1] = s2; }
  __syncthreads();
  if (tid == 0) {
    float a = 0.f, bsum = 0.f;
#pragma unroll
    for (int w = 0; w < BLK / 64; ++w) { a += red[w * 2]; bsum += red[w * 2 + 1]; }
    atomicAdd(&stats[c], a);
    atomicAdd(&stats[C_ + c], bsum);
  }

  if constexpr (STORE_Y) {
    const long ybase = ((long)(b * C_ + c)) * TY + t0 + toff;
    if (toff + R <= TL) {
#pragma unroll
      for (int q = 0; q < R; q += 4)
        *(float4*)&y[ybase + q] = *(float4*)&acc[q];
    } else {
#pragma unroll
      for (int r = 0; r < R; ++r)
        if (toff + r < TL) y[ybase + r] = acc[r];
    }
  }
}

// Kernel B: stats -> per-channel scale/shift
__global__ void finalize_stats(const float* __restrict__ stats,
                               const float* __restrict__ gamma,
                               const float* __restrict__ beta,
                               float* __restrict__ ss) {
  const int c = threadIdx.x;
  if (c < C_) {
    const double N = (double)B_ * (double)T1;
    const double mean = (double)stats[c] / N;
    const double var = (double)stats[C_ + c] / N - mean * mean;
    const float scale = gamma[c] * (float)(1.0 / sqrt(var + (double)EPS));
    const float shift = beta[c] - (float)mean * scale;
    ss[c] = scale;
    ss[C_ + c] = shift;
  }
}

// Kernel C: u = |y*scale+shift| ; out = conv(u, wlow) + blow
// RECOMP=false: yin = padded y buffer. RECOMP=true: yin = x (recompute conv1).
template <bool RECOMP>
__global__ __launch_bounds__(BLK) void bn_abs_conv2(
    const float* __restrict__ yin, const float* __restrict__ wband,
    const float* __restrict__ wlow, const float* __restrict__ blow,
    const float* __restrict__ ss, float* __restrict__ out) {
  __shared__ alignas(16) float us[SZU];
  __shared__ alignas(16) float wsm2[K2 + 16];

  const int tid = threadIdx.x;
  const int chunk = blockIdx.x, c = blockIdx.y, b = blockIdx.z;
  const int t0 = chunk * TILE;
  const int TL = min(TILE, T2 - t0);   // valid outputs
  const int UL = TL + K2 - 1;          // u values needed
  const float scale = ss[c], shift = ss[C_ + c];

  for (int i = tid; i < K2; i += BLK) wsm2[i] = wlow[c * K2 + i];

  if constexpr (!RECOMP) {
    const long ybase = ((long)(b * C_ + c)) * TY + t0;
    for (int i = tid * 4; i < SZU; i += BLK * 4) {
      float4 v;
      if (i + 4 <= UL) v = *(const float4*)&yin[ybase + i];
      else {
        v.x = (i + 0 < UL) ? yin[ybase + i + 0] : 0.f;
        v.y = (i + 1 < UL) ? yin[ybase + i + 1] : 0.f;
        v.z = (i + 2 < UL) ? yin[ybase + i + 2] : 0.f;
        v.w = (i + 3 < UL) ? yin[ybase + i + 3] : 0.f;
      }
      v.x = fabsf(fmaf(v.x, scale, shift));
      v.y = fabsf(fmaf(v.y, scale, shift));
      v.z = fabsf(fmaf(v.z, scale, shift));
      v.w = fabsf(fmaf(v.w, scale, shift));
      lds_st4(us, i, v);
    }
    __syncthreads();
  } else {
    __shared__ alignas(16) float xs2[SZ2];
    __shared__ alignas(16) float wsm1[K1 + 16];
    const int XL = UL + K1 - 1;
    const long xbase = ((long)(b * C_ + c)) * T_ + t0;
    for (int i = tid; i < K1; i += BLK) wsm1[i] = wband[c * K1 + i];
    for (int i = tid * 4; i < SZ2; i += BLK * 4) {
      float4 v;
      if (i + 4 <= XL) v = *(const float4*)&yin[xbase + i];
      else {
        v.x = (i + 0 < XL) ? yin[xbase + i + 0] : 0.f;
        v.y = (i + 1 < XL) ? yin[xbase + i + 1] : 0.f;
        v.z = (i + 2 < XL) ? yin[xbase + i + 2] : 0.f;
        v.w = (i + 3 < XL) ? yin[xbase + i + 3] : 0.f;
      }
      lds_st4(xs2, i, v);
    }
    __syncthreads();
    {
      const int toff = tid * R;
      float acc[R];
      fir_window<K1>(xs2, wsm1, toff, acc);
#pragma unroll
      for (int q = 0; q < R; q += 4) {
        float4 v;
        v.x = fabsf(fmaf(acc[q + 0], scale, shift));
        v.y = fabsf(fmaf(acc[q + 1], scale, shift));
        v.z = fabsf(fmaf(acc[q + 2], scale, shift));
        v.w = fabsf(fmaf(acc[q + 3], scale, shift));
        lds_st4(us, toff + q, v);
      }
      if (tid < K2 - 1) {          // tail u positions TILE..TILE+K2-2
        const int p = TILE + tid;
        if (p < UL) {
          float a = 0.f;
          for (int k = 0; k < K1; ++k) a = fmaf(lds_ld(xs2, p + k), wsm1[k], a);
          lds_st(us, p, fabsf(fmaf(a, scale, shift)));
        }
      }
    }
    __syncthreads();
  }

  const int toff = tid * R;
  float acc[R];
  fir_window<K2>(us, wsm2, toff, acc);
  const float bl = blow[c];
#pragma unroll
  for (int r = 0; r < R; ++r) acc[r] += bl;

  const long obase = ((long)(b * C_ + c)) * T2 + t0 + toff;
  if (toff + R <= TL) {
#pragma unroll
    for (int q = 0; q < R; q += 4)
      *(float4*)&out[obase + q] = *(float4*)&acc[q];
  } else {
#pragma unroll
    for (int r = 0; r < R; ++r)
      if (toff + r < TL) out[obase + r] = acc[r];
  }
}

extern "C" void kernel_launch(void* const* d_in, const int* in_sizes, int n_in,
                              void* d_out, int out_size, void* d_ws, size_t ws_size,
                              hipStream_t stream) {
  const float* x = (const float*)d_in[0];
  const float* wband = (const float*)d_in[1];
  const float* gamma = (const float*)d_in[2];
  const float* beta = (const float*)d_in[3];
  const float* wlow = (const float*)d_in[4];
  const float* blow = (const float*)d_in[5];
  float* out = (float*)d_out;
  float* ws = (float*)d_ws;

  const size_t yfloats = (size_t)B_ * C_ * TY;            // 40,763,392
  const bool bigws = ws_size >= (yfloats + 256) * sizeof(float);

  float* ybuf = ws;
  float* stats = bigws ? (ws + yfloats) : ws;   // 128 floats: sum, sumsq
  float* ss = stats + 128;                      // 128 floats: scale, shift

  zero_stats<<<1, 128, 0, stream>>>(stats);

  dim3 grid1(NCH1, C_, B_);
  if (bigws)
    conv1_stats<true><<<grid1, BLK, 0, stream>>>(x, wband, ybuf, stats);
  else
    conv1_stats<false><<<grid1, BLK, 0, stream>>>(x, wband, nullptr, stats);

  finalize_stats<<<1, 64, 0, stream>>>(stats, gamma, beta, ss);

  dim3 grid2(NCH2, C_, B_);
  if (bigws)
    bn_abs_conv2<false><<<grid2, BLK, 0, stream>>>(ybuf, wband, wlow, blow, ss, out);
  else
    bn_abs_conv2<true><<<grid2, BLK, 0, stream>>>(x, wband, wlow, blow, ss, out);
}